// Round 11
// baseline (237.414 us; speedup 1.0000x reference)
//
#include <hip/hip_runtime.h>
#include <cstddef>

#define B_ 4
#define L_ 1024
#define H_ 16
#define DH_ 64
#define HID_ 1024
#define HEADSZ_ 4194304   // B*H*L*DH

typedef short bf16x8 __attribute__((ext_vector_type(8)));
typedef short bf16x4 __attribute__((ext_vector_type(4)));
typedef float f32x4  __attribute__((ext_vector_type(4)));

#define QSCALE_ 0.18033688011112042f   // 0.125 * log2(e)  (folded into q at GEMM epilogue)
#define SCLAMP_ 144269.5f              // 1e5 * log2(e)    (clamp bound in log2 domain)

__device__ __forceinline__ short f2bf(float f) {
    unsigned u = __float_as_uint(f);
    u = (u + 0x7fffu + ((u >> 16) & 1u)) >> 16;   // RNE
    return (short)u;
}
__device__ __forceinline__ float bf2f(short s) {
    return __uint_as_float(((unsigned)(unsigned short)s) << 16);
}
// NOTE: v_cvt_pk_bf16_f32 inline asm is BANNED — proven NaN source on this
// toolchain by the r7 single-atom probe (baseline+pk4-only failed).
__device__ __forceinline__ float exp2_fast(float x) {
#if __has_builtin(__builtin_amdgcn_exp2f)
    return __builtin_amdgcn_exp2f(x);
#else
    return __expf(0.6931471805599453f * x);
#endif
}
__device__ __forceinline__ void glds16(const short* g, short* l) {
    __builtin_amdgcn_global_load_lds(
        (const __attribute__((address_space(1))) unsigned int*)g,
        (__attribute__((address_space(3))) unsigned int*)l, 16, 0, 0);
}

// ---------------------------------------------------------------------------
// Merged prep: [0,2048) xcast | [2048,3072) wcast4 | [3072,3136) relcast.
// rel image: PLAIN chunk-linear layout, values pre-scaled by 8 (exact pow2)
// for the log2-domain softmax; attn reads it directly from global (L2-hot).
// Nonexistent tail row 2047 is zero-filled.
// ---------------------------------------------------------------------------
__global__ __launch_bounds__(256) void prep_k(
    const float* __restrict__ x,
    const float* __restrict__ Wq, const float* __restrict__ Wk,
    const float* __restrict__ Wv, const float* __restrict__ Wo,
    const float* __restrict__ rel,
    short* __restrict__ xb, short* __restrict__ Wt, short* __restrict__ relimg)
{
    const int bid = blockIdx.x;
    const int t   = threadIdx.x;
    if (bid < 2048) {                      // x fp32 -> bf16
        const int base = (bid * 256 + t) << 3;
        float4 f0 = *(const float4*)&x[base];
        float4 f1 = *(const float4*)&x[base + 4];
        bf16x8 p;
        p[0] = f2bf(f0.x); p[1] = f2bf(f0.y); p[2] = f2bf(f0.z); p[3] = f2bf(f0.w);
        p[4] = f2bf(f1.x); p[5] = f2bf(f1.y); p[6] = f2bf(f1.z); p[7] = f2bf(f1.w);
        *(bf16x8*)&xb[base] = p;
    } else if (bid < 3072) {               // W transpose+cast: Wt[n][k] = W[k][n]
        const int idx = bid - 2048;
        const int z = idx >> 8, tile = idx & 255;
        const float* W = (z == 0) ? Wq : (z == 1) ? Wk : (z == 2) ? Wv : Wo;
        short* dstb = Wt + (size_t)z * HID_ * HID_;
        __shared__ float T[64][65];
        const int k0 = (tile & 15) << 6, n0 = (tile >> 4) << 6;
        const int r  = t & 63;
        const int cg = t >> 6;
#pragma unroll
        for (int u = 0; u < 4; ++u) {
            float4 f = *(const float4*)&W[(size_t)(k0 + r) * HID_ + n0 + (cg << 4) + (u << 2)];
            T[r][(cg << 4) + (u << 2) + 0] = f.x;
            T[r][(cg << 4) + (u << 2) + 1] = f.y;
            T[r][(cg << 4) + (u << 2) + 2] = f.z;
            T[r][(cg << 4) + (u << 2) + 3] = f.w;
        }
        __syncthreads();
        bf16x8 p0, p1;
#pragma unroll
        for (int j = 0; j < 8; ++j) p0[j] = f2bf(T[(cg << 4) + j][r]);
#pragma unroll
        for (int j = 0; j < 8; ++j) p1[j] = f2bf(T[(cg << 4) + 8 + j][r]);
        short* dst = &dstb[(size_t)(n0 + r) * HID_ + k0 + (cg << 4)];
        *(bf16x8*)dst       = p0;
        *(bf16x8*)(dst + 8) = p1;
    } else {                               // rel -> plain chunk-linear bf16, x8
        const int base = ((bid - 3072) * 256 + t) << 3;
        if (base >= 2048 * 64) return;
        if (base >= 2047 * 64) {           // nonexistent row 2047 -> zeros
            *(bf16x8*)&relimg[base] = (bf16x8){0, 0, 0, 0, 0, 0, 0, 0};
            return;
        }
        float4 f0 = *(const float4*)&rel[base];
        float4 f1 = *(const float4*)&rel[base + 4];
        bf16x8 p;
        p[0] = f2bf(f0.x * 8.f); p[1] = f2bf(f0.y * 8.f);
        p[2] = f2bf(f0.z * 8.f); p[3] = f2bf(f0.w * 8.f);
        p[4] = f2bf(f1.x * 8.f); p[5] = f2bf(f1.y * 8.f);
        p[6] = f2bf(f1.z * 8.f); p[7] = f2bf(f1.w * 8.f);
        *(bf16x8*)&relimg[base] = p;
    }
}

// ---------------------------------------------------------------------------
// bf16 MFMA GEMM, 128 x (NT*32) tile, BK=32, glds staging, source-permuted
// swizzle (slot g holds kgroup g^((row>>1)&3)). NT=4: 128-wide; NT=2: 64.
// mode 0: fp32 out (bias b0). mode 1: bf16 qkv (q plain*QSCALE / k image / v image).
// ---------------------------------------------------------------------------
template <int NT>
__global__ __launch_bounds__(256, 3) void gemm_glds_k(
    const short* __restrict__ A, const short* __restrict__ Wt,
    const float* __restrict__ b0, const float* __restrict__ b1,
    const float* __restrict__ b2, void* __restrict__ outv,
    int K, int mode)
{
    constexpr int BN = NT * 32;
    __shared__ short As[128 * 32];
    __shared__ short Bs[BN * 32];

    const int t    = threadIdx.x;
    const int lane = t & 63, w = t >> 6;
    const int m0   = blockIdx.y << 7, n0 = blockIdx.x * BN;
    const int fr   = lane & 15, qd = lane >> 4;
    const int wm0  = (w & 1) << 6, wn0 = (w >> 1) * (NT << 4);

    const int srow = lane >> 2;                      // 0..15 within 16-row chunk
    const int sg   = (lane & 3) ^ ((lane >> 3) & 3); // swizzled source kgroup
    const int slot = qd ^ ((fr >> 1) & 3);           // read-side slot group

    f32x4 acc[4][NT];
#pragma unroll
    for (int i = 0; i < 4; ++i)
#pragma unroll
        for (int j = 0; j < NT; ++j) acc[i][j] = (f32x4){0.f, 0.f, 0.f, 0.f};

    const short* aBase  = A  + (size_t)(m0 + w * 32 + srow) * K + sg * 8;
    const short* aBase2 = aBase + (size_t)16 * K;
    const short* bBase  = Wt + (size_t)(n0 + w * (BN / 4) + srow) * K + sg * 8;
    const short* bBase2 = bBase + (size_t)16 * K;
    short* aDst  = &As[(w * 32) * 32];
    short* aDst2 = &As[(w * 32 + 16) * 32];
    short* bDst  = &Bs[(w * (BN / 4)) * 32];
    short* bDst2 = &Bs[(w * (BN / 4) + 16) * 32];

    for (int k0 = 0; k0 < K; k0 += 32) {
        __syncthreads();
        glds16(aBase + k0, aDst);
        glds16(aBase2 + k0, aDst2);
        glds16(bBase + k0, bDst);
        if (NT == 4) glds16(bBase2 + k0, bDst2);
        __syncthreads();

        bf16x8 af[4], bfv[NT];
#pragma unroll
        for (int mt = 0; mt < 4; ++mt)
            af[mt] = *(const bf16x8*)&As[((wm0 + (mt << 4) + fr) << 5) + (slot << 3)];
#pragma unroll
        for (int nt = 0; nt < NT; ++nt)
            bfv[nt] = *(const bf16x8*)&Bs[((wn0 + (nt << 4) + fr) << 5) + (slot << 3)];
#pragma unroll
        for (int mt = 0; mt < 4; ++mt)
#pragma unroll
            for (int nt = 0; nt < NT; ++nt)
                acc[mt][nt] = __builtin_amdgcn_mfma_f32_16x16x32_bf16(
                    af[mt], bfv[nt], acc[mt][nt], 0, 0, 0);
    }

#pragma unroll
    for (int nt = 0; nt < NT; ++nt) {
        const int coln = n0 + wn0 + (nt << 4) + fr;
        float bias;
        if (mode == 0) bias = b0[coln];
        else {
            const int t3 = coln >> 10;
            bias = (t3 == 0 ? b0 : t3 == 1 ? b1 : b2)[coln & 1023];
        }
#pragma unroll
        for (int mt = 0; mt < 4; ++mt)
#pragma unroll
            for (int rg = 0; rg < 4; ++rg) {
                const int row = m0 + wm0 + (mt << 4) + (qd << 2) + rg;
                float val = acc[mt][nt][rg] + bias;
                if (mode == 0) {
                    ((float*)outv)[(size_t)row * HID_ + coln] = val;
                } else {
                    const int t3 = coln >> 10;
                    if (t3 == 0) val *= QSCALE_;   // fold 0.125*log2e into q
                    const int h  = (coln >> 6) & 15;
                    const int d  = coln & 63;
                    const int bb = row >> 10, l = row & 1023;
                    const size_t bhoff = ((size_t)(bb * H_ + h)) << 16;
                    size_t dst;
                    if (t3 == 0)        // q: plain [b,h,l,d]
                        dst = bhoff + ((size_t)l << 6) + d;
                    else if (t3 == 1)   // k: swizzled tile image
                        dst = (size_t)HEADSZ_ + bhoff + ((size_t)(l >> 6) << 12)
                            + ((l & 63) << 6) + ((((d >> 3) ^ (l & 7))) << 3) + (d & 7);
                    else                // v: transposed swizzled tile image [d][j=l]
                        dst = 2 * (size_t)HEADSZ_ + bhoff + ((size_t)(l >> 6) << 12)
                            + ((size_t)d << 6) + (((((l >> 3) & 7) ^ (d & 7))) << 3) + (l & 7);
                    ((short*)outv)[dst] = f2bf(val);
                }
            }
    }
}

// ---------------------------------------------------------------------------
// MFMA attention, S^T/O^T formulation. Per block (b,h,64-row Q tile), 4 waves.
// Full round-0 design, pk4/cvtpk REMOVED (manual f2bf packs only):
//  * LDS 33792 B -> 4 blocks/CU, grid 1024 = exactly one round, no tail.
//    - Rl staging dropped: rel fragments read straight from global (plain
//      image, L2-hot), issued right after the staging barrier so S^T hides
//      the latency.
//    - P overlaid on Ks (stride 64, XOR swizzle on 4-short groups; write
//      group u^=2*(fr&7), read 8-short base (g^(fr&7))<<3 — bijective,
//      logical groups 2g,2g+1 land contiguously). 3rd __syncthreads per jt:
//      after all waves' S^T reads of Ks, before the P-store reuses it.
//      P rows are wave-private, so exp->PV needs no further sync.
//  * Softmax in log2 domain: q carries 0.125*log2e (GEMM epilogue), rel
//    carries x8 (prep), so e = exp2(clamp(acc_s) + tv), zero multiplies.
// ---------------------------------------------------------------------------
__global__ __launch_bounds__(256, 4) void attn_mfma_k(
    const short* __restrict__ q, const short* __restrict__ kimg,
    const short* __restrict__ vimg, const short* __restrict__ relimg,
    short* __restrict__ ctx)
{
    __shared__ __align__(16) short Ks[64 * 64];   // K tile; becomes P after barrier 3
    __shared__ __align__(16) short Vt[64 * 64];
    __shared__ __align__(16) short Ts[2 * 64 * 68];   // [par][c][ii]

    const int t    = threadIdx.x;
    const int i0   = blockIdx.x << 6;
    const int h    = blockIdx.y;
    const int b    = blockIdx.z;
    const size_t bh = (size_t)(b * H_ + h) << 16;
    const int lane = t & 63, w = t >> 6;
    const int fr   = lane & 15, qd = lane >> 4;
    const int m16  = i0 >> 6;
    const int iiB  = (w << 4) + (qd << 2);   // T-producer col base
    const int ii   = (w << 4) + fr;          // this thread's S^T row
    const int soff = w * 1024 + lane * 8;
    const int swz  = (fr & 7) << 1;          // P swizzle (ii&7 == fr&7)

    // Q fragments (A-layout for T production, B-layout for S^T — same regs)
    bf16x8 af[2];
#pragma unroll
    for (int hh = 0; hh < 2; ++hh)
        af[hh] = *(const bf16x8*)&q[bh + ((size_t)(i0 + (w << 4) + fr) << 6)
                                    + (((hh << 2) + qd) << 3)];

    // prologue: T chunk m16+16 -> parity m16&1 (rel direct from global; Ts
    // columns are wave-private so no barrier needed)
    {
        const short* rc = relimg + ((size_t)(m16 + 16) << 12);
        f32x4 acc_t[4];
#pragma unroll
        for (int i = 0; i < 4; ++i) acc_t[i] = (f32x4){0.f, 0.f, 0.f, 0.f};
#pragma unroll
        for (int hh = 0; hh < 2; ++hh) {
            const int g = (hh << 2) + qd;
#pragma unroll
            for (int rt = 0; rt < 4; ++rt) {
                bf16x8 br = *(const bf16x8*)&rc[(((rt << 4) + fr) << 6) + (g << 3)];
                acc_t[rt] = __builtin_amdgcn_mfma_f32_16x16x32_bf16(af[hh], br, acc_t[rt], 0, 0, 0);
            }
        }
        const int pu = m16 & 1;
#pragma unroll
        for (int rt = 0; rt < 4; ++rt) {
            bf16x4 p;
            p[0] = f2bf(acc_t[rt][0]); p[1] = f2bf(acc_t[rt][1]);
            p[2] = f2bf(acc_t[rt][2]); p[3] = f2bf(acc_t[rt][3]);
            *(bf16x4*)&Ts[pu * 4352 + ((rt << 4) + fr) * 68 + iiB] = p;
        }
    }

    f32x4 acc_o[4];   // O^T: acc_o[mt][rg] = O[ii][d = mt*16+qd*4+rg]
#pragma unroll
    for (int i = 0; i < 4; ++i) acc_o[i] = (f32x4){0.f, 0.f, 0.f, 0.f};
    float den = 0.f;

    for (int jt = 0; jt < 16; ++jt) {
        const int mlow = m16 + 15 - jt;
        const int pl   = mlow & 1;

        __syncthreads();   // prev tile's Ks(P)/Vt reads complete
        glds16(kimg + bh + ((size_t)jt << 12) + soff,       Ks + w * 1024);
        glds16(kimg + bh + ((size_t)jt << 12) + soff + 512, Ks + w * 1024 + 512);
        glds16(vimg + bh + ((size_t)jt << 12) + soff,       Vt + w * 1024);
        glds16(vimg + bh + ((size_t)jt << 12) + soff + 512, Vt + w * 1024 + 512);
        __syncthreads();   // staged tiles visible

        // rel fragments for this jt: direct global loads, latency hidden by S^T
        const short* rc = relimg + ((size_t)mlow << 12);
        bf16x8 brr[2][4];
#pragma unroll
        for (int hh = 0; hh < 2; ++hh) {
            const int g = (hh << 2) + qd;
#pragma unroll
            for (int rt = 0; rt < 4; ++rt)
                brr[hh][rt] = *(const bf16x8*)&rc[(((rt << 4) + fr) << 6) + (g << 3)];
        }

        // S^T = K·Q^T : acc_s[mt] rows jj = mt*16+qd*4+rg, col ii = w*16+fr
        f32x4 acc_s[4];
#pragma unroll
        for (int i = 0; i < 4; ++i) acc_s[i] = (f32x4){0.f, 0.f, 0.f, 0.f};
#pragma unroll
        for (int hh = 0; hh < 2; ++hh) {
            const int g = (hh << 2) + qd;
#pragma unroll
            for (int mt = 0; mt < 4; ++mt) {
                const int rb = (mt << 4) + fr;
                bf16x8 bk = *(const bf16x8*)&Ks[(rb << 6) + ((g ^ (rb & 7)) << 3)];
                acc_s[mt] = __builtin_amdgcn_mfma_f32_16x16x32_bf16(bk, af[hh], acc_s[mt], 0, 0, 0);
            }
        }

        __syncthreads();   // all waves' Ks reads done -> region becomes P

        // new T chunk (rows 64*mlow..+63), from pre-issued global fragments
        {
            f32x4 acc_t[4];
#pragma unroll
            for (int i = 0; i < 4; ++i) acc_t[i] = (f32x4){0.f, 0.f, 0.f, 0.f};
#pragma unroll
            for (int hh = 0; hh < 2; ++hh)
#pragma unroll
                for (int rt = 0; rt < 4; ++rt)
                    acc_t[rt] = __builtin_amdgcn_mfma_f32_16x16x32_bf16(
                        af[hh], brr[hh][rt], acc_t[rt], 0, 0, 0);
#pragma unroll
            for (int rt = 0; rt < 4; ++rt) {
                bf16x4 p;
                p[0] = f2bf(acc_t[rt][0]); p[1] = f2bf(acc_t[rt][1]);
                p[2] = f2bf(acc_t[rt][2]); p[3] = f2bf(acc_t[rt][3]);
                *(bf16x4*)&Ts[pl * 4352 + ((rt << 4) + fr) * 68 + iiB] = p;
            }
        }
        // Ts wave-private: intra-wave lgkm ordering suffices

        // exp2 + T gather + P row-store into Ks region (stride 64, swizzled)
#pragma unroll
        for (int mt = 0; mt < 4; ++mt) {
            bf16x4 pk;
#pragma unroll
            for (int rg = 0; rg < 4; ++rg) {
                const int jj  = (mt << 4) + (qd << 2) + rg;
                const int c   = ii - jj + 63;                 // [0,126]
                const int par = pl ^ (c >> 6);
                const float tv = bf2f(Ts[par * 4352 + (c & 63) * 68 + ii]);
                const float s  = fminf(fmaxf(acc_s[mt][rg], -SCLAMP_), SCLAMP_);
                const float e  = exp2_fast(s + tv);
                den += e;
                pk[rg] = f2bf(e);
            }
            *(bf16x4*)&Ks[(ii << 6) + ((((mt << 2) + qd) ^ swz) << 2)] = pk;
        }

        // O^T += V^T·P^T : a = Vt rows (d), b = P row ii (jj-contig, deswizzled)
#pragma unroll
        for (int hh = 0; hh < 2; ++hh) {
            const int g = (hh << 2) + qd;
            bf16x8 bp = *(const bf16x8*)&Ks[(ii << 6) + ((g ^ (fr & 7)) << 3)];
#pragma unroll
            for (int mt = 0; mt < 4; ++mt) {
                const int rb = (mt << 4) + fr;
                bf16x8 av = *(const bf16x8*)&Vt[(rb << 6) + ((g ^ (rb & 7)) << 3)];
                acc_o[mt] = __builtin_amdgcn_mfma_f32_16x16x32_bf16(av, bp, acc_o[mt], 0, 0, 0);
            }
        }
    }

    // den: full row ii = sum over the 4 qd groups (lanes ^16, ^32)
    den += __shfl_xor(den, 16);
    den += __shfl_xor(den, 32);
    const float inv = 1.0f / den;

    const int l = i0 + ii;
#pragma unroll
    for (int mt = 0; mt < 4; ++mt) {
        bf16x4 o;
#pragma unroll
        for (int rg = 0; rg < 4; ++rg) o[rg] = f2bf(acc_o[mt][rg] * inv);
        *(bf16x4*)&ctx[((size_t)(b * L_ + l) << 10) + (h << 6) + (mt << 4) + (qd << 2)] = o;
    }
}

// ---------------------------------------------------------------------------
extern "C" void kernel_launch(void* const* d_in, const int* in_sizes, int n_in,
                              void* d_out, int out_size, void* d_ws, size_t ws_size,
                              hipStream_t stream)
{
    const float* x   = (const float*)d_in[0];
    const float* Wq  = (const float*)d_in[1];
    const float* bq  = (const float*)d_in[2];
    const float* Wk  = (const float*)d_in[3];
    const float* bk  = (const float*)d_in[4];
    const float* Wv  = (const float*)d_in[5];
    const float* bv  = (const float*)d_in[6];
    const float* Wo  = (const float*)d_in[7];
    const float* bo  = (const float*)d_in[8];
    const float* rel = (const float*)d_in[9];
    float* out = (float*)d_out;

    short* xb     = (short*)d_ws;                       // 4096x1024 bf16
    short* qkv    = xb + (size_t)HEADSZ_;               // q plain, k image, v image
    short* cw     = qkv + (size_t)3 * HEADSZ_;          // ctx bf16 [B*L, HID]
    short* wt     = cw + (size_t)HEADSZ_;               // 4 x HID^2 bf16
    short* relimg = wt + (size_t)4 * HID_ * HID_;       // 32 x 4096 shorts (plain, x8)

    const dim3 tb(256);

    prep_k<<<dim3(3136), tb, 0, stream>>>(x, Wq, Wk, Wv, Wo, rel, xb, wt, relimg);

    // fused QKV GEMM: N=3072, tile 128x128, BK=32
    gemm_glds_k<4><<<dim3(24, 32), tb, 0, stream>>>(
        xb, wt, bq, bk, bv, qkv, HID_, 1);

    attn_mfma_k<<<dim3(16, H_, B_), tb, 0, stream>>>(
        qkv, qkv + HEADSZ_, qkv + 2 * (size_t)HEADSZ_, relimg, cw);

    // output GEMM: N=1024, tile 128x64 -> 512 blocks (2/CU)
    gemm_glds_k<2><<<dim3(16, 32), tb, 0, stream>>>(
        cw, wt + (size_t)3 * HID_ * HID_, bo, bo, bo, out, HID_, 0);
}